// Round 8
// baseline (416.880 us; speedup 1.0000x reference)
//
#include <hip/hip_runtime.h>
#include <hip/hip_fp16.h>
#include <math.h>

#define N_NODES 100000
#define N_EDGES 1600000
#define E_TOT   (N_EDGES + N_NODES)

// bucketed CSR build
#define NB     512          // buckets
#define NPB    196          // dst-nodes per bucket (512*196 = 100352 >= N)
#define BCAP   4096         // capacity per bucket (mean 3332, +13 sigma)
#define BIN_CH 4096         // edges per bin_k workgroup
#define NBIN_WG ((E_TOT + BIN_CH - 1) / BIN_CH)

__device__ __forceinline__ float wexp(float v) {
    v = v > 0.f ? v : 0.2f * v;
    return __expf(v);
}

// ---------------------------------------------------------------------------
// GEMM1 (LDS-tiled): h1[N,128] = x[N,128] @ W1[128,128], fp16 out; fused
// alpha_src/alpha_dst. Block = 64 nodes; k-tiles of 64; coalesced staging.
// ---------------------------------------------------------------------------
__global__ __launch_bounds__(256) void gemm1_k(
    const float* __restrict__ x, const float* __restrict__ W1,
    const float* __restrict__ as1, const float* __restrict__ ad1,
    __half* __restrict__ h1h, float* __restrict__ asrc, float* __restrict__ adst)
{
    __shared__ float xs[64][65];      // 16.6 KB
    __shared__ float Wsh[64][128];    // 32 KB
    const int t = threadIdx.x;
    const int nbase = blockIdx.x * 64;
    const int c4 = t & 31;            // cols 4*c4 .. 4*c4+3
    const int ng = t >> 5;            // nodes ng*8 .. ng*8+7

    float acc[8][4];
#pragma unroll
    for (int i = 0; i < 8; ++i)
#pragma unroll
        for (int j = 0; j < 4; ++j) acc[i][j] = 0.f;

    for (int kt = 0; kt < 128; kt += 64) {
        __syncthreads();
        {
            int r = t >> 4;
            int c = (t & 15) * 4;
#pragma unroll
            for (int p = 0; p < 4; ++p) {
                int row = p * 16 + r;
                int gr = nbase + row; if (gr > N_NODES - 1) gr = N_NODES - 1;
                float4 v = *(const float4*)(x + (size_t)gr * 128 + kt + c);
                xs[row][c + 0] = v.x; xs[row][c + 1] = v.y;
                xs[row][c + 2] = v.z; xs[row][c + 3] = v.w;
            }
        }
        {
            int r = t >> 5;
            int c = (t & 31) * 4;
#pragma unroll
            for (int p = 0; p < 8; ++p) {
                int row = p * 8 + r;
                *(float4*)&Wsh[row][c] = *(const float4*)(W1 + (size_t)(kt + row) * 128 + c);
            }
        }
        __syncthreads();

#pragma unroll 4
        for (int k = 0; k < 64; ++k) {
            float4 w = *(const float4*)&Wsh[k][c4 * 4];
            float x0 = xs[ng * 8 + 0][k], x1 = xs[ng * 8 + 1][k];
            float x2 = xs[ng * 8 + 2][k], x3 = xs[ng * 8 + 3][k];
            float x4 = xs[ng * 8 + 4][k], x5 = xs[ng * 8 + 5][k];
            float x6 = xs[ng * 8 + 6][k], x7 = xs[ng * 8 + 7][k];
            acc[0][0] += x0 * w.x; acc[0][1] += x0 * w.y; acc[0][2] += x0 * w.z; acc[0][3] += x0 * w.w;
            acc[1][0] += x1 * w.x; acc[1][1] += x1 * w.y; acc[1][2] += x1 * w.z; acc[1][3] += x1 * w.w;
            acc[2][0] += x2 * w.x; acc[2][1] += x2 * w.y; acc[2][2] += x2 * w.z; acc[2][3] += x2 * w.w;
            acc[3][0] += x3 * w.x; acc[3][1] += x3 * w.y; acc[3][2] += x3 * w.z; acc[3][3] += x3 * w.w;
            acc[4][0] += x4 * w.x; acc[4][1] += x4 * w.y; acc[4][2] += x4 * w.z; acc[4][3] += x4 * w.w;
            acc[5][0] += x5 * w.x; acc[5][1] += x5 * w.y; acc[5][2] += x5 * w.z; acc[5][3] += x5 * w.w;
            acc[6][0] += x6 * w.x; acc[6][1] += x6 * w.y; acc[6][2] += x6 * w.z; acc[6][3] += x6 * w.w;
            acc[7][0] += x7 * w.x; acc[7][1] += x7 * w.y; acc[7][2] += x7 * w.z; acc[7][3] += x7 * w.w;
        }
    }

    float4 as4 = ((const float4*)as1)[c4];
    float4 ad4 = ((const float4*)ad1)[c4];
#pragma unroll
    for (int i = 0; i < 8; ++i) {
        int node = nbase + ng * 8 + i;
        float ax = acc[i][0], ay = acc[i][1], az = acc[i][2], aw = acc[i][3];
        if (node < N_NODES) {
            __half2* row = (__half2*)(h1h + (size_t)node * 128);
            row[2 * c4]     = __floats2half2_rn(ax, ay);
            row[2 * c4 + 1] = __floats2half2_rn(az, aw);
        }
        float ps = ax * as4.x + ay * as4.y + az * as4.z + aw * as4.w;
        float pd = ax * ad4.x + ay * ad4.y + az * ad4.z + aw * ad4.w;
#pragma unroll
        for (int off = 1; off < 16; off <<= 1) {
            ps += __shfl_xor(ps, off);
            pd += __shfl_xor(pd, off);
        }
        if ((t & 15) == 0 && node < N_NODES) {
            int h = c4 >> 4;
            asrc[node * 2 + h] = ps;
            adst[node * 2 + h] = pd;
        }
    }
}

// ---------------------------------------------------------------------------
// CSR build, phase 1: bin edges by dst bucket.
// ---------------------------------------------------------------------------
__global__ __launch_bounds__(256) void bin_k(
    const int* __restrict__ ei, int* __restrict__ bcur, unsigned* __restrict__ bdata)
{
    __shared__ int hist[NB];
    __shared__ int base[NB];
    const int t = threadIdx.x;
    const int e0 = blockIdx.x * BIN_CH;
    const int n = min(BIN_CH, E_TOT - e0);

    for (int b = t; b < NB; b += 256) hist[b] = 0;
    __syncthreads();

    for (int i = t; i < n; i += 256) {
        int e = e0 + i;
        int d = (e < N_EDGES) ? ei[N_EDGES + e] : e - N_EDGES;
        atomicAdd(&hist[d / NPB], 1);
    }
    __syncthreads();

    for (int b = t; b < NB; b += 256) {
        int c = hist[b];
        base[b] = c ? atomicAdd(&bcur[b], c) : 0;
        hist[b] = 0;      // reuse as local cursor
    }
    __syncthreads();

    for (int i = t; i < n; i += 256) {
        int e = e0 + i;
        int s, d;
        if (e < N_EDGES) { s = ei[e]; d = ei[N_EDGES + e]; }
        else             { s = d = e - N_EDGES; }
        int b  = d / NPB;
        int dl = d - b * NPB;
        int pos = base[b] + atomicAdd(&hist[b], 1);
        if (pos < BCAP)
            bdata[(size_t)b * BCAP + pos] = (unsigned)s | ((unsigned)dl << 17);
    }
}

// ---------------------------------------------------------------------------
// CSR build, phase 2a: exclusive scan of bucket counts (1 wg x 512 threads).
// ---------------------------------------------------------------------------
__global__ __launch_bounds__(512) void scanb_k(
    const int* __restrict__ bcur, int* __restrict__ bbase)
{
    __shared__ int a[NB], b_[NB];
    int t = threadIdx.x;
    int v = bcur[t];
    a[t] = v;
    __syncthreads();
    int* src = a; int* dst = b_;
    for (int off = 1; off < NB; off <<= 1) {
        dst[t] = (t >= off) ? src[t - off] + src[t] : src[t];
        __syncthreads();
        int* tmp = src; src = dst; dst = tmp;
    }
    bbase[t] = src[t] - v;   // exclusive
}

// ---------------------------------------------------------------------------
// CSR build, phase 2b: wg per bucket -> row_start + csr_src (contiguous).
// Also zero-fills the 16-int pad past csr_src[E_TOT] (for aligned int4 reads).
// ---------------------------------------------------------------------------
__global__ __launch_bounds__(256) void build_k(
    const unsigned* __restrict__ bdata, const int* __restrict__ bcur,
    const int* __restrict__ bbase, int* __restrict__ row_start,
    int* __restrict__ csr_src)
{
    __shared__ unsigned rec[BCAP];     // 16 KB
    __shared__ int hist[256];
    __shared__ int excl[NPB];
    __shared__ int lcur[NPB];
    const int t = threadIdx.x;
    const int b = blockIdx.x;
    const int cnt = min(bcur[b], BCAP);
    const int bb = bbase[b];

    if (b == 0 && t < 16) csr_src[E_TOT + t] = 0;   // pad for int4 group reads

    hist[t] = 0;
    if (t < NPB) lcur[t] = 0;
    __syncthreads();

    for (int i = t; i < cnt; i += 256) {
        unsigned r = bdata[(size_t)b * BCAP + i];
        rec[i] = r;
        atomicAdd(&hist[r >> 17], 1);
    }
    __syncthreads();

    int v = hist[t];
    __syncthreads();
    for (int off = 1; off < 256; off <<= 1) {
        int y = (t >= off) ? hist[t - off] : 0;
        __syncthreads();
        hist[t] += y;
        __syncthreads();
    }
    if (t < NPB) excl[t] = hist[t] - v;
    __syncthreads();

    int node = b * NPB + t;
    if (t < NPB && node <= N_NODES) row_start[node] = bb + excl[t];

    for (int i = t; i < cnt; i += 256) {
        unsigned r = rec[i];
        int dl = r >> 17;
        int s  = r & 0x1FFFF;
        int slot = atomicAdd(&lcur[dl], 1);
        csr_src[bb + excl[dl] + slot] = s;
    }
}

// ---------------------------------------------------------------------------
// Fused layer-1 aggregation: 8-wide masked groups (aligned int4 index loads,
// invalid slots clamped to anchor row with weight 0) -> 8 gather chains in
// flight. asrc loaded as float2 (both heads, select by h). fp16 out.
// ---------------------------------------------------------------------------
__global__ __launch_bounds__(256) void fagg1_k(
    const int* __restrict__ csr_src, const int* __restrict__ row_start,
    const float* __restrict__ asrc, const float* __restrict__ adst,
    const __half* __restrict__ h1h, const float* __restrict__ b1,
    __half* __restrict__ out1h)
{
    int node = blockIdx.x * 4 + (threadIdx.x >> 6);
    int L = threadIdx.x & 63;
    int h = L >> 5;
    int b = row_start[node], e = row_start[node + 1];
    float ad = adst[node * 2 + h];
    const __half2* H = (const __half2*)h1h;
    const float2* A2 = (const float2*)asrc;
    const int sA = csr_src[b];          // anchor (deg>=1 via self-loop)

    float ax[8], ay[8], dd[8];
#pragma unroll
    for (int i = 0; i < 8; ++i) { ax[i] = 0.f; ay[i] = 0.f; dd[i] = 0.f; }

    for (int j = (b & ~7); j < e; j += 8) {
        int4 q0 = *(const int4*)(csr_src + j);
        int4 q1 = *(const int4*)(csr_src + j + 4);
        int ss[8] = {q0.x, q0.y, q0.z, q0.w, q1.x, q1.y, q1.z, q1.w};
#pragma unroll
        for (int i = 0; i < 8; ++i) {
            bool valid = (j + i >= b) && (j + i < e);
            int s = valid ? ss[i] : sA;
            float2 av = A2[s];
            float w = valid ? wexp((h ? av.y : av.x) + ad) : 0.f;
            float2 xv = __half22float2(H[(size_t)s * 64 + L]);
            ax[i] += w * xv.x; ay[i] += w * xv.y; dd[i] += w;
        }
    }

    float den = ((dd[0] + dd[1]) + (dd[2] + dd[3])) + ((dd[4] + dd[5]) + (dd[6] + dd[7]));
    float sx  = ((ax[0] + ax[1]) + (ax[2] + ax[3])) + ((ax[4] + ax[5]) + (ax[6] + ax[7]));
    float sy  = ((ay[0] + ay[1]) + (ay[2] + ay[3])) + ((ay[4] + ay[5]) + (ay[6] + ay[7]));
    float inv = 1.f / (den + 1e-16f);
    float2 bb = ((const float2*)b1)[L];
    float vx = sx * inv + bb.x;
    float vy = sy * inv + bb.y;
    vx = vx > 0.f ? vx : expm1f(vx);
    vy = vy > 0.f ? vy : expm1f(vy);
    ((__half2*)(out1h + (size_t)node * 128))[L] = __floats2half2_rn(vx, vy);
}

// ---------------------------------------------------------------------------
// GEMM2 (LDS-tiled): h2[N,64pad fp16] = out1[N,128] @ W2[128,40].
// ---------------------------------------------------------------------------
__global__ __launch_bounds__(256) void gemm2_k(
    const __half* __restrict__ in1h, const float* __restrict__ W2,
    const float* __restrict__ as2, const float* __restrict__ ad2,
    __half* __restrict__ h2h, float* __restrict__ asrc, float* __restrict__ adst)
{
    __shared__ float xs[64][65];      // 16.6 KB
    __shared__ float Wsh[64][64];     // 16 KB
    __shared__ float as_s[64], ad_s[64];
    const int t = threadIdx.x;
    const int nbase = blockIdx.x * 64;
    const int c4 = t & 15;
    const int ng = t >> 4;

    if (t < 64) {
        as_s[t] = (t < 40) ? as2[t] : 0.f;
        ad_s[t] = (t < 40) ? ad2[t] : 0.f;
    }

    float acc[4][4];
#pragma unroll
    for (int i = 0; i < 4; ++i)
#pragma unroll
        for (int j = 0; j < 4; ++j) acc[i][j] = 0.f;

    for (int kt = 0; kt < 128; kt += 64) {
        __syncthreads();
        {
            int r = t >> 4;
            int c = (t & 15) * 4;
#pragma unroll
            for (int p = 0; p < 4; ++p) {
                int row = p * 16 + r;
                int gr = nbase + row; if (gr > N_NODES - 1) gr = N_NODES - 1;
                const __half2* src = (const __half2*)(in1h + (size_t)gr * 128 + kt + c);
                float2 f01 = __half22float2(src[0]);
                float2 f23 = __half22float2(src[1]);
                xs[row][c + 0] = f01.x; xs[row][c + 1] = f01.y;
                xs[row][c + 2] = f23.x; xs[row][c + 3] = f23.y;
            }
        }
        for (int i = t; i < 4096; i += 256) {
            int k = i >> 6, c = i & 63;
            Wsh[k][c] = (c < 40) ? W2[(size_t)(kt + k) * 40 + c] : 0.f;
        }
        __syncthreads();

#pragma unroll 4
        for (int k = 0; k < 64; ++k) {
            float4 w = *(const float4*)&Wsh[k][c4 * 4];
            float x0 = xs[ng * 4 + 0][k], x1 = xs[ng * 4 + 1][k];
            float x2 = xs[ng * 4 + 2][k], x3 = xs[ng * 4 + 3][k];
            acc[0][0] += x0 * w.x; acc[0][1] += x0 * w.y; acc[0][2] += x0 * w.z; acc[0][3] += x0 * w.w;
            acc[1][0] += x1 * w.x; acc[1][1] += x1 * w.y; acc[1][2] += x1 * w.z; acc[1][3] += x1 * w.w;
            acc[2][0] += x2 * w.x; acc[2][1] += x2 * w.y; acc[2][2] += x2 * w.z; acc[2][3] += x2 * w.w;
            acc[3][0] += x3 * w.x; acc[3][1] += x3 * w.y; acc[3][2] += x3 * w.z; acc[3][3] += x3 * w.w;
        }
    }

    float4 as4 = *(const float4*)&as_s[c4 * 4];
    float4 ad4 = *(const float4*)&ad_s[c4 * 4];
#pragma unroll
    for (int i = 0; i < 4; ++i) {
        int node = nbase + ng * 4 + i;
        float axx = acc[i][0], ayy = acc[i][1], azz = acc[i][2], aww = acc[i][3];
        if (node < N_NODES) {
            __half2* row = (__half2*)(h2h + (size_t)node * 64);
            row[2 * c4]     = __floats2half2_rn(axx, ayy);
            row[2 * c4 + 1] = __floats2half2_rn(azz, aww);
        }
        float ps = axx * as4.x + ayy * as4.y + azz * as4.z + aww * as4.w;
        float pd = axx * ad4.x + ayy * ad4.y + azz * ad4.z + aww * ad4.w;
#pragma unroll
        for (int off = 1; off < 16; off <<= 1) {
            ps += __shfl_xor(ps, off);
            pd += __shfl_xor(pd, off);
        }
        if ((t & 15) == 0 && node < N_NODES) {
            asrc[node] = ps;
            adst[node] = pd;
        }
    }
}

// ---------------------------------------------------------------------------
// Fused layer-2 aggregation + bias + log_softmax: same 8-wide masked groups.
// ---------------------------------------------------------------------------
__global__ __launch_bounds__(256) void fagg2_k(
    const int* __restrict__ csr_src, const int* __restrict__ row_start,
    const float* __restrict__ asrc, const float* __restrict__ adst,
    const __half* __restrict__ h2h, const float* __restrict__ b2,
    float* __restrict__ out)
{
    int node = blockIdx.x * 4 + (threadIdx.x >> 6);
    int L = threadIdx.x & 63;
    bool act = L < 40;
    int col = act ? L : 0;
    int b = row_start[node], e = row_start[node + 1];
    float ad = adst[node];
    const int sA = csr_src[b];

    float aa[8], dd[8];
#pragma unroll
    for (int i = 0; i < 8; ++i) { aa[i] = 0.f; dd[i] = 0.f; }

    for (int j = (b & ~7); j < e; j += 8) {
        int4 q0 = *(const int4*)(csr_src + j);
        int4 q1 = *(const int4*)(csr_src + j + 4);
        int ss[8] = {q0.x, q0.y, q0.z, q0.w, q1.x, q1.y, q1.z, q1.w};
#pragma unroll
        for (int i = 0; i < 8; ++i) {
            bool valid = (j + i >= b) && (j + i < e);
            int s = valid ? ss[i] : sA;
            float w = valid ? wexp(asrc[s] + ad) : 0.f;
            float xv = __half2float(h2h[(size_t)s * 64 + col]);
            aa[i] += w * xv; dd[i] += w;
        }
    }

    float den = ((dd[0] + dd[1]) + (dd[2] + dd[3])) + ((dd[4] + dd[5]) + (dd[6] + dd[7]));
    float acc = ((aa[0] + aa[1]) + (aa[2] + aa[3])) + ((aa[4] + aa[5]) + (aa[6] + aa[7]));
    float v = act ? acc / (den + 1e-16f) + b2[L] : -1e30f;
    float mx = v;
#pragma unroll
    for (int off = 32; off; off >>= 1) mx = fmaxf(mx, __shfl_xor(mx, off));
    float ex = act ? __expf(v - mx) : 0.f;
#pragma unroll
    for (int off = 32; off; off >>= 1) ex += __shfl_xor(ex, off);
    if (act) out[(size_t)node * 40 + L] = v - mx - logf(ex);
}

// ---------------------------------------------------------------------------
extern "C" void kernel_launch(void* const* d_in, const int* in_sizes, int n_in,
                              void* d_out, int out_size, void* d_ws, size_t ws_size,
                              hipStream_t stream)
{
    const float* x   = (const float*)d_in[0];
    const int*   ei  = (const int*)d_in[1];
    const float* W1  = (const float*)d_in[2];
    const float* as1 = (const float*)d_in[3];
    const float* ad1 = (const float*)d_in[4];
    const float* b1  = (const float*)d_in[5];
    const float* W2  = (const float*)d_in[6];
    const float* as2 = (const float*)d_in[7];
    const float* ad2 = (const float*)d_in[8];
    const float* b2  = (const float*)d_in[9];
    float* out = (float*)d_out;

    float* ws = (float*)d_ws;
    // workspace layout (4B units); total ~23.8M = 95.2 MB
    __half* h1h   = (__half*)ws;                  // N*128 halves; reused as h2h (N*64 halves)
    __half* out1h = (__half*)(ws + 6400000);      // N*128 halves
    float* asrc1 = ws + 19200000;                 // 2N
    float* adst1 = ws + 19400000;                 // 2N
    float* asrc2 = ws + 19600000;                 // N
    float* adst2 = ws + 19700000;                 // N
    int* bcur      = (int*)(ws + 19800000);       // NB
    int* bbase     = (int*)(ws + 19801000);       // NB
    int* row_start = (int*)(ws + 19802000);       // N+1
    int* csr_src   = (int*)(ws + 19910000);       // E_TOT + 16 pad
    unsigned* bdata = (unsigned*)(ws + 21700000); // NB*BCAP = 2.1M

    // zero bucket cursors only (2 KB)
    hipMemsetAsync(bcur, 0, NB * sizeof(int), stream);

    // CSR build: bin -> scan -> build
    bin_k<<<NBIN_WG, 256, 0, stream>>>(ei, bcur, bdata);
    scanb_k<<<1, 512, 0, stream>>>(bcur, bbase);
    build_k<<<NB, 256, 0, stream>>>(bdata, bcur, bbase, row_start, csr_src);

    // layer 1
    gemm1_k<<<1563, 256, 0, stream>>>(x, W1, as1, ad1, h1h, asrc1, adst1);
    fagg1_k<<<25000, 256, 0, stream>>>(csr_src, row_start, asrc1, adst1, h1h, b1, out1h);

    // layer 2 (h2h reuses h1h region, stride 64 halves = one 128B line)
    __half* h2h = h1h;
    gemm2_k<<<1563, 256, 0, stream>>>(out1h, W2, as2, ad2, h2h, asrc2, adst2);
    fagg2_k<<<25000, 256, 0, stream>>>(csr_src, row_start, asrc2, adst2, h2h, b2, out);
}

// Round 9
// 342.724 us; speedup vs baseline: 1.2164x; 1.2164x over previous
//
#include <hip/hip_runtime.h>
#include <hip/hip_fp16.h>
#include <math.h>

#define N_NODES 100000
#define N_EDGES 1600000
#define E_TOT   (N_EDGES + N_NODES)

// bucketed CSR build
#define NB     512          // buckets
#define NPB    196          // dst-nodes per bucket (512*196 = 100352 >= N)
#define BCAP   4096         // capacity per bucket (mean 3332, +13 sigma)
#define BIN_CH 4096         // edges per bin_k workgroup
#define NBIN_WG ((E_TOT + BIN_CH - 1) / BIN_CH)

__device__ __forceinline__ float wexp(float v) {
    v = v > 0.f ? v : 0.2f * v;
    return __expf(v);
}

// ---------------------------------------------------------------------------
// GEMM1 (LDS-tiled): h1[N,128] = x[N,128] @ W1[128,128], fp16 out; fused
// alpha_src/alpha_dst. Block = 64 nodes; k-tiles of 64; coalesced staging.
// ---------------------------------------------------------------------------
__global__ __launch_bounds__(256) void gemm1_k(
    const float* __restrict__ x, const float* __restrict__ W1,
    const float* __restrict__ as1, const float* __restrict__ ad1,
    __half* __restrict__ h1h, float* __restrict__ asrc, float* __restrict__ adst)
{
    __shared__ float xs[64][65];      // 16.6 KB
    __shared__ float Wsh[64][128];    // 32 KB
    const int t = threadIdx.x;
    const int nbase = blockIdx.x * 64;
    const int c4 = t & 31;            // cols 4*c4 .. 4*c4+3
    const int ng = t >> 5;            // nodes ng*8 .. ng*8+7

    float acc[8][4];
#pragma unroll
    for (int i = 0; i < 8; ++i)
#pragma unroll
        for (int j = 0; j < 4; ++j) acc[i][j] = 0.f;

    for (int kt = 0; kt < 128; kt += 64) {
        __syncthreads();
        {
            int r = t >> 4;
            int c = (t & 15) * 4;
#pragma unroll
            for (int p = 0; p < 4; ++p) {
                int row = p * 16 + r;
                int gr = nbase + row; if (gr > N_NODES - 1) gr = N_NODES - 1;
                float4 v = *(const float4*)(x + (size_t)gr * 128 + kt + c);
                xs[row][c + 0] = v.x; xs[row][c + 1] = v.y;
                xs[row][c + 2] = v.z; xs[row][c + 3] = v.w;
            }
        }
        {
            int r = t >> 5;
            int c = (t & 31) * 4;
#pragma unroll
            for (int p = 0; p < 8; ++p) {
                int row = p * 8 + r;
                *(float4*)&Wsh[row][c] = *(const float4*)(W1 + (size_t)(kt + row) * 128 + c);
            }
        }
        __syncthreads();

#pragma unroll 4
        for (int k = 0; k < 64; ++k) {
            float4 w = *(const float4*)&Wsh[k][c4 * 4];
            float x0 = xs[ng * 8 + 0][k], x1 = xs[ng * 8 + 1][k];
            float x2 = xs[ng * 8 + 2][k], x3 = xs[ng * 8 + 3][k];
            float x4 = xs[ng * 8 + 4][k], x5 = xs[ng * 8 + 5][k];
            float x6 = xs[ng * 8 + 6][k], x7 = xs[ng * 8 + 7][k];
            acc[0][0] += x0 * w.x; acc[0][1] += x0 * w.y; acc[0][2] += x0 * w.z; acc[0][3] += x0 * w.w;
            acc[1][0] += x1 * w.x; acc[1][1] += x1 * w.y; acc[1][2] += x1 * w.z; acc[1][3] += x1 * w.w;
            acc[2][0] += x2 * w.x; acc[2][1] += x2 * w.y; acc[2][2] += x2 * w.z; acc[2][3] += x2 * w.w;
            acc[3][0] += x3 * w.x; acc[3][1] += x3 * w.y; acc[3][2] += x3 * w.z; acc[3][3] += x3 * w.w;
            acc[4][0] += x4 * w.x; acc[4][1] += x4 * w.y; acc[4][2] += x4 * w.z; acc[4][3] += x4 * w.w;
            acc[5][0] += x5 * w.x; acc[5][1] += x5 * w.y; acc[5][2] += x5 * w.z; acc[5][3] += x5 * w.w;
            acc[6][0] += x6 * w.x; acc[6][1] += x6 * w.y; acc[6][2] += x6 * w.z; acc[6][3] += x6 * w.w;
            acc[7][0] += x7 * w.x; acc[7][1] += x7 * w.y; acc[7][2] += x7 * w.z; acc[7][3] += x7 * w.w;
        }
    }

    float4 as4 = ((const float4*)as1)[c4];
    float4 ad4 = ((const float4*)ad1)[c4];
#pragma unroll
    for (int i = 0; i < 8; ++i) {
        int node = nbase + ng * 8 + i;
        float ax = acc[i][0], ay = acc[i][1], az = acc[i][2], aw = acc[i][3];
        if (node < N_NODES) {
            __half2* row = (__half2*)(h1h + (size_t)node * 128);
            row[2 * c4]     = __floats2half2_rn(ax, ay);
            row[2 * c4 + 1] = __floats2half2_rn(az, aw);
        }
        float ps = ax * as4.x + ay * as4.y + az * as4.z + aw * as4.w;
        float pd = ax * ad4.x + ay * ad4.y + az * ad4.z + aw * ad4.w;
#pragma unroll
        for (int off = 1; off < 16; off <<= 1) {
            ps += __shfl_xor(ps, off);
            pd += __shfl_xor(pd, off);
        }
        if ((t & 15) == 0 && node < N_NODES) {
            int h = c4 >> 4;
            asrc[node * 2 + h] = ps;
            adst[node * 2 + h] = pd;
        }
    }
}

// ---------------------------------------------------------------------------
// CSR build, phase 1: bin edges by dst bucket.
// ---------------------------------------------------------------------------
__global__ __launch_bounds__(256) void bin_k(
    const int* __restrict__ ei, int* __restrict__ bcur, unsigned* __restrict__ bdata)
{
    __shared__ int hist[NB];
    __shared__ int base[NB];
    const int t = threadIdx.x;
    const int e0 = blockIdx.x * BIN_CH;
    const int n = min(BIN_CH, E_TOT - e0);

    for (int b = t; b < NB; b += 256) hist[b] = 0;
    __syncthreads();

    for (int i = t; i < n; i += 256) {
        int e = e0 + i;
        int d = (e < N_EDGES) ? ei[N_EDGES + e] : e - N_EDGES;
        atomicAdd(&hist[d / NPB], 1);
    }
    __syncthreads();

    for (int b = t; b < NB; b += 256) {
        int c = hist[b];
        base[b] = c ? atomicAdd(&bcur[b], c) : 0;
        hist[b] = 0;      // reuse as local cursor
    }
    __syncthreads();

    for (int i = t; i < n; i += 256) {
        int e = e0 + i;
        int s, d;
        if (e < N_EDGES) { s = ei[e]; d = ei[N_EDGES + e]; }
        else             { s = d = e - N_EDGES; }
        int b  = d / NPB;
        int dl = d - b * NPB;
        int pos = base[b] + atomicAdd(&hist[b], 1);
        if (pos < BCAP)
            bdata[(size_t)b * BCAP + pos] = (unsigned)s | ((unsigned)dl << 17);
    }
}

// ---------------------------------------------------------------------------
// CSR build, phase 2a: exclusive scan of bucket counts (1 wg x 512 threads).
// ---------------------------------------------------------------------------
__global__ __launch_bounds__(512) void scanb_k(
    const int* __restrict__ bcur, int* __restrict__ bbase)
{
    __shared__ int a[NB], b_[NB];
    int t = threadIdx.x;
    int v = bcur[t];
    a[t] = v;
    __syncthreads();
    int* src = a; int* dst = b_;
    for (int off = 1; off < NB; off <<= 1) {
        dst[t] = (t >= off) ? src[t - off] + src[t] : src[t];
        __syncthreads();
        int* tmp = src; src = dst; dst = tmp;
    }
    bbase[t] = src[t] - v;   // exclusive
}

// ---------------------------------------------------------------------------
// CSR build, phase 2b: wg per bucket -> row_start + csr_src (contiguous).
// ---------------------------------------------------------------------------
__global__ __launch_bounds__(256) void build_k(
    const unsigned* __restrict__ bdata, const int* __restrict__ bcur,
    const int* __restrict__ bbase, int* __restrict__ row_start,
    int* __restrict__ csr_src)
{
    __shared__ unsigned rec[BCAP];     // 16 KB
    __shared__ int hist[256];
    __shared__ int excl[NPB];
    __shared__ int lcur[NPB];
    const int t = threadIdx.x;
    const int b = blockIdx.x;
    const int cnt = min(bcur[b], BCAP);
    const int bb = bbase[b];

    hist[t] = 0;
    if (t < NPB) lcur[t] = 0;
    __syncthreads();

    for (int i = t; i < cnt; i += 256) {
        unsigned r = bdata[(size_t)b * BCAP + i];
        rec[i] = r;
        atomicAdd(&hist[r >> 17], 1);
    }
    __syncthreads();

    int v = hist[t];
    __syncthreads();
    for (int off = 1; off < 256; off <<= 1) {
        int y = (t >= off) ? hist[t - off] : 0;
        __syncthreads();
        hist[t] += y;
        __syncthreads();
    }
    if (t < NPB) excl[t] = hist[t] - v;
    __syncthreads();

    int node = b * NPB + t;
    if (t < NPB && node <= N_NODES) row_start[node] = bb + excl[t];

    for (int i = t; i < cnt; i += 256) {
        unsigned r = rec[i];
        int dl = r >> 17;
        int s  = r & 0x1FFFF;
        int slot = atomicAdd(&lcur[dl], 1);
        csr_src[bb + excl[dl] + slot] = s;
    }
}

// ---------------------------------------------------------------------------
// Edge-weight pass, layer 1: wave per node; lane strides CSR row.
// Per edge: one 8B asrc gather + 2 exp; writes UNNORMALIZED w (float2, both
// heads, CSR-ordered/coalesced) + per-node denominators (shfl reduce).
// ---------------------------------------------------------------------------
__global__ __launch_bounds__(256) void edgew1_k(
    const int* __restrict__ csr_src, const int* __restrict__ row_start,
    const float2* __restrict__ asrc2, const float2* __restrict__ adst2,
    float2* __restrict__ wn, float2* __restrict__ dsum)
{
    int node = blockIdx.x * 4 + (threadIdx.x >> 6);
    int L = threadIdx.x & 63;
    int b = row_start[node], e = row_start[node + 1];
    float2 ad = adst2[node];
    float s0 = 0.f, s1 = 0.f;
    for (int j = b + L; j < e; j += 64) {
        float2 av = asrc2[csr_src[j]];
        float w0 = wexp(av.x + ad.x);
        float w1 = wexp(av.y + ad.y);
        wn[j] = make_float2(w0, w1);
        s0 += w0; s1 += w1;
    }
#pragma unroll
    for (int off = 32; off; off >>= 1) {
        s0 += __shfl_xor(s0, off);
        s1 += __shfl_xor(s1, off);
    }
    if (L == 0) dsum[node] = make_float2(s0, s1);
}

// ---------------------------------------------------------------------------
// Edge-weight pass, layer 2 (single head).
// ---------------------------------------------------------------------------
__global__ __launch_bounds__(256) void edgew2_k(
    const int* __restrict__ csr_src, const int* __restrict__ row_start,
    const float* __restrict__ asrc, const float* __restrict__ adst,
    float* __restrict__ wn, float* __restrict__ dsum)
{
    int node = blockIdx.x * 4 + (threadIdx.x >> 6);
    int L = threadIdx.x & 63;
    int b = row_start[node], e = row_start[node + 1];
    float ad = adst[node];
    float s = 0.f;
    for (int j = b + L; j < e; j += 64) {
        float w = wexp(asrc[csr_src[j]] + ad);
        wn[j] = w;
        s += w;
    }
#pragma unroll
    for (int off = 32; off; off >>= 1) s += __shfl_xor(s, off);
    if (L == 0) dsum[node] = s;
}

// ---------------------------------------------------------------------------
// Fused layer-1 aggregation, pure gather: per edge = csr load + broadcast
// wn load + H-row gather + 2 FMA. No exp, no asrc gather, no denom accum.
// Normalize (from dsum) + bias + ELU epilogue; fp16 out.
// ---------------------------------------------------------------------------
__global__ __launch_bounds__(256) void fagg1_k(
    const int* __restrict__ csr_src, const int* __restrict__ row_start,
    const float2* __restrict__ wn, const float2* __restrict__ dsum,
    const __half* __restrict__ h1h, const float* __restrict__ b1,
    __half* __restrict__ out1h)
{
    int node = blockIdx.x * 4 + (threadIdx.x >> 6);
    int L = threadIdx.x & 63;
    int h = L >> 5;
    int b = row_start[node], e = row_start[node + 1];
    const __half2* H = (const __half2*)h1h;

    float2 a0 = make_float2(0.f, 0.f), a1 = a0, a2 = a0, a3 = a0;

    int j = b;
    for (; j + 3 < e; j += 4) {
        int s0 = csr_src[j], s1 = csr_src[j + 1], s2 = csr_src[j + 2], s3 = csr_src[j + 3];
        float2 u0 = wn[j], u1 = wn[j + 1], u2 = wn[j + 2], u3 = wn[j + 3];
        float2 x0 = __half22float2(H[(size_t)s0 * 64 + L]);
        float2 x1 = __half22float2(H[(size_t)s1 * 64 + L]);
        float2 x2 = __half22float2(H[(size_t)s2 * 64 + L]);
        float2 x3 = __half22float2(H[(size_t)s3 * 64 + L]);
        float w0 = h ? u0.y : u0.x;
        float w1 = h ? u1.y : u1.x;
        float w2 = h ? u2.y : u2.x;
        float w3 = h ? u3.y : u3.x;
        a0.x += w0 * x0.x; a0.y += w0 * x0.y;
        a1.x += w1 * x1.x; a1.y += w1 * x1.y;
        a2.x += w2 * x2.x; a2.y += w2 * x2.y;
        a3.x += w3 * x3.x; a3.y += w3 * x3.y;
    }
    for (; j < e; ++j) {
        int s = csr_src[j];
        float2 u = wn[j];
        float w = h ? u.y : u.x;
        float2 xv = __half22float2(H[(size_t)s * 64 + L]);
        a0.x += w * xv.x; a0.y += w * xv.y;
    }

    float2 ds = dsum[node];
    float inv = 1.f / ((h ? ds.y : ds.x) + 1e-16f);
    float2 bb = ((const float2*)b1)[L];
    float vx = (a0.x + a1.x + a2.x + a3.x) * inv + bb.x;
    float vy = (a0.y + a1.y + a2.y + a3.y) * inv + bb.y;
    vx = vx > 0.f ? vx : expm1f(vx);
    vy = vy > 0.f ? vy : expm1f(vy);
    ((__half2*)(out1h + (size_t)node * 128))[L] = __floats2half2_rn(vx, vy);
}

// ---------------------------------------------------------------------------
// GEMM2 (LDS-tiled): h2[N,64pad fp16] = out1[N,128] @ W2[128,40].
// ---------------------------------------------------------------------------
__global__ __launch_bounds__(256) void gemm2_k(
    const __half* __restrict__ in1h, const float* __restrict__ W2,
    const float* __restrict__ as2, const float* __restrict__ ad2,
    __half* __restrict__ h2h, float* __restrict__ asrc, float* __restrict__ adst)
{
    __shared__ float xs[64][65];      // 16.6 KB
    __shared__ float Wsh[64][64];     // 16 KB
    __shared__ float as_s[64], ad_s[64];
    const int t = threadIdx.x;
    const int nbase = blockIdx.x * 64;
    const int c4 = t & 15;
    const int ng = t >> 4;

    if (t < 64) {
        as_s[t] = (t < 40) ? as2[t] : 0.f;
        ad_s[t] = (t < 40) ? ad2[t] : 0.f;
    }

    float acc[4][4];
#pragma unroll
    for (int i = 0; i < 4; ++i)
#pragma unroll
        for (int j = 0; j < 4; ++j) acc[i][j] = 0.f;

    for (int kt = 0; kt < 128; kt += 64) {
        __syncthreads();
        {
            int r = t >> 4;
            int c = (t & 15) * 4;
#pragma unroll
            for (int p = 0; p < 4; ++p) {
                int row = p * 16 + r;
                int gr = nbase + row; if (gr > N_NODES - 1) gr = N_NODES - 1;
                const __half2* src = (const __half2*)(in1h + (size_t)gr * 128 + kt + c);
                float2 f01 = __half22float2(src[0]);
                float2 f23 = __half22float2(src[1]);
                xs[row][c + 0] = f01.x; xs[row][c + 1] = f01.y;
                xs[row][c + 2] = f23.x; xs[row][c + 3] = f23.y;
            }
        }
        for (int i = t; i < 4096; i += 256) {
            int k = i >> 6, c = i & 63;
            Wsh[k][c] = (c < 40) ? W2[(size_t)(kt + k) * 40 + c] : 0.f;
        }
        __syncthreads();

#pragma unroll 4
        for (int k = 0; k < 64; ++k) {
            float4 w = *(const float4*)&Wsh[k][c4 * 4];
            float x0 = xs[ng * 4 + 0][k], x1 = xs[ng * 4 + 1][k];
            float x2 = xs[ng * 4 + 2][k], x3 = xs[ng * 4 + 3][k];
            acc[0][0] += x0 * w.x; acc[0][1] += x0 * w.y; acc[0][2] += x0 * w.z; acc[0][3] += x0 * w.w;
            acc[1][0] += x1 * w.x; acc[1][1] += x1 * w.y; acc[1][2] += x1 * w.z; acc[1][3] += x1 * w.w;
            acc[2][0] += x2 * w.x; acc[2][1] += x2 * w.y; acc[2][2] += x2 * w.z; acc[2][3] += x2 * w.w;
            acc[3][0] += x3 * w.x; acc[3][1] += x3 * w.y; acc[3][2] += x3 * w.z; acc[3][3] += x3 * w.w;
        }
    }

    float4 as4 = *(const float4*)&as_s[c4 * 4];
    float4 ad4 = *(const float4*)&ad_s[c4 * 4];
#pragma unroll
    for (int i = 0; i < 4; ++i) {
        int node = nbase + ng * 4 + i;
        float axx = acc[i][0], ayy = acc[i][1], azz = acc[i][2], aww = acc[i][3];
        if (node < N_NODES) {
            __half2* row = (__half2*)(h2h + (size_t)node * 64);
            row[2 * c4]     = __floats2half2_rn(axx, ayy);
            row[2 * c4 + 1] = __floats2half2_rn(azz, aww);
        }
        float ps = axx * as4.x + ayy * as4.y + azz * as4.z + aww * as4.w;
        float pd = axx * ad4.x + ayy * ad4.y + azz * ad4.z + aww * ad4.w;
#pragma unroll
        for (int off = 1; off < 16; off <<= 1) {
            ps += __shfl_xor(ps, off);
            pd += __shfl_xor(pd, off);
        }
        if ((t & 15) == 0 && node < N_NODES) {
            asrc[node] = ps;
            adst[node] = pd;
        }
    }
}

// ---------------------------------------------------------------------------
// Fused layer-2 aggregation (pure gather) + bias + log_softmax.
// ---------------------------------------------------------------------------
__global__ __launch_bounds__(256) void fagg2_k(
    const int* __restrict__ csr_src, const int* __restrict__ row_start,
    const float* __restrict__ wn, const float* __restrict__ dsum,
    const __half* __restrict__ h2h, const float* __restrict__ b2,
    float* __restrict__ out)
{
    int node = blockIdx.x * 4 + (threadIdx.x >> 6);
    int L = threadIdx.x & 63;
    bool act = L < 40;
    int col = act ? L : 0;
    int b = row_start[node], e = row_start[node + 1];

    float a0 = 0.f, a1 = 0.f, a2 = 0.f, a3 = 0.f;

    int j = b;
    for (; j + 3 < e; j += 4) {
        int s0 = csr_src[j], s1 = csr_src[j + 1], s2 = csr_src[j + 2], s3 = csr_src[j + 3];
        float w0 = wn[j], w1 = wn[j + 1], w2 = wn[j + 2], w3 = wn[j + 3];
        float x0 = __half2float(h2h[(size_t)s0 * 64 + col]);
        float x1 = __half2float(h2h[(size_t)s1 * 64 + col]);
        float x2 = __half2float(h2h[(size_t)s2 * 64 + col]);
        float x3 = __half2float(h2h[(size_t)s3 * 64 + col]);
        a0 += w0 * x0;
        a1 += w1 * x1;
        a2 += w2 * x2;
        a3 += w3 * x3;
    }
    for (; j < e; ++j) {
        int s = csr_src[j];
        float w = wn[j];
        float xv = __half2float(h2h[(size_t)s * 64 + col]);
        a0 += w * xv;
    }

    float den = dsum[node];
    float acc = (a0 + a1) + (a2 + a3);
    float v = act ? acc / (den + 1e-16f) + b2[L] : -1e30f;
    float mx = v;
#pragma unroll
    for (int off = 32; off; off >>= 1) mx = fmaxf(mx, __shfl_xor(mx, off));
    float ex = act ? __expf(v - mx) : 0.f;
#pragma unroll
    for (int off = 32; off; off >>= 1) ex += __shfl_xor(ex, off);
    if (act) out[(size_t)node * 40 + L] = v - mx - logf(ex);
}

// ---------------------------------------------------------------------------
extern "C" void kernel_launch(void* const* d_in, const int* in_sizes, int n_in,
                              void* d_out, int out_size, void* d_ws, size_t ws_size,
                              hipStream_t stream)
{
    const float* x   = (const float*)d_in[0];
    const int*   ei  = (const int*)d_in[1];
    const float* W1  = (const float*)d_in[2];
    const float* as1 = (const float*)d_in[3];
    const float* ad1 = (const float*)d_in[4];
    const float* b1  = (const float*)d_in[5];
    const float* W2  = (const float*)d_in[6];
    const float* as2 = (const float*)d_in[7];
    const float* ad2 = (const float*)d_in[8];
    const float* b2  = (const float*)d_in[9];
    float* out = (float*)d_out;

    float* ws = (float*)d_ws;
    // workspace layout (4B units); total ~28.5M = 114 MB
    __half* h1h   = (__half*)ws;                  // N*128 halves; reused as h2h (N*64 halves)
    __half* out1h = (__half*)(ws + 6400000);      // N*128 halves
    float* asrc1 = ws + 19200000;                 // 2N
    float* adst1 = ws + 19400000;                 // 2N
    float* asrc2 = ws + 19600000;                 // N
    float* adst2 = ws + 19700000;                 // N
    float* dsum1 = ws + 19810000;                 // 2N (float2 per node)
    float* dsum2 = ws + 20010000;                 // N
    int* bcur      = (int*)(ws + 20110000);       // NB
    int* bbase     = (int*)(ws + 20111000);       // NB
    int* row_start = (int*)(ws + 20112000);       // N+1
    int* csr_src   = (int*)(ws + 20220000);       // E_TOT
    unsigned* bdata = (unsigned*)(ws + 22000000); // NB*BCAP = 2.1M
    float* wn1     = ws + 24100000;               // E_TOT*2 (float2); wn2 reuses
    float* wn2     = wn1;                         // E_TOT (float), after fagg1

    // zero bucket cursors only (2 KB)
    hipMemsetAsync(bcur, 0, NB * sizeof(int), stream);

    // CSR build: bin -> scan -> build
    bin_k<<<NBIN_WG, 256, 0, stream>>>(ei, bcur, bdata);
    scanb_k<<<1, 512, 0, stream>>>(bcur, bbase);
    build_k<<<NB, 256, 0, stream>>>(bdata, bcur, bbase, row_start, csr_src);

    // layer 1
    gemm1_k<<<1563, 256, 0, stream>>>(x, W1, as1, ad1, h1h, asrc1, adst1);
    edgew1_k<<<25000, 256, 0, stream>>>(csr_src, row_start,
                                        (const float2*)asrc1, (const float2*)adst1,
                                        (float2*)wn1, (float2*)dsum1);
    fagg1_k<<<25000, 256, 0, stream>>>(csr_src, row_start,
                                       (const float2*)wn1, (const float2*)dsum1,
                                       h1h, b1, out1h);

    // layer 2 (h2h reuses h1h region; wn2 reuses wn1 region)
    __half* h2h = h1h;
    gemm2_k<<<1563, 256, 0, stream>>>(out1h, W2, as2, ad2, h2h, asrc2, adst2);
    edgew2_k<<<25000, 256, 0, stream>>>(csr_src, row_start, asrc2, adst2, wn2, dsum2);
    fagg2_k<<<25000, 256, 0, stream>>>(csr_src, row_start, wn2, dsum2, h2h, b2, out);
}

// Round 10
// 286.149 us; speedup vs baseline: 1.4569x; 1.1977x over previous
//
#include <hip/hip_runtime.h>
#include <hip/hip_fp16.h>
#include <math.h>

#define N_NODES 100000
#define N_EDGES 1600000
#define E_TOT   (N_EDGES + N_NODES)

// bucketed CSR build
#define NB     512          // buckets
#define NPB    196          // dst-nodes per bucket (512*196 = 100352 >= N)
#define BCAP   4096         // capacity per bucket (mean 3332, +13 sigma)
#define BIN_CH 4096         // edges per bin_k workgroup
#define NBIN_WG ((E_TOT + BIN_CH - 1) / BIN_CH)

typedef __attribute__((ext_vector_type(8))) short short8v;   // 8 bf16
typedef __attribute__((ext_vector_type(4))) float float4v;

__device__ __forceinline__ float wexp(float v) {
    v = v > 0.f ? v : 0.2f * v;
    return __expf(v);
}

__device__ __forceinline__ unsigned short f2bf(float f) {
    unsigned u = __float_as_uint(f);
    return (unsigned short)((u + 0x7FFFu + ((u >> 16) & 1u)) >> 16);
}

// ---------------------------------------------------------------------------
// xprep: x fp32 -> bf16 (row-major, same layout). 4 elems/thread.
// ---------------------------------------------------------------------------
__global__ __launch_bounds__(256) void xprep_k(
    const float* __restrict__ x, unsigned short* __restrict__ xb)
{
    int gid = blockIdx.x * 256 + threadIdx.x;     // covers N*128/4 exactly
    float4 v = ((const float4*)x)[gid];
    ushort4 o;
    o.x = f2bf(v.x); o.y = f2bf(v.y); o.z = f2bf(v.z); o.w = f2bf(v.w);
    ((ushort4*)xb)[gid] = o;
}

// ---------------------------------------------------------------------------
// w1prep: W1 -> bf16 fragment order [kstep][colfrag][lane][8] so gemm1's
// B-frag is one contiguous 16B load per lane. 32 KB total.
// frag layout (16x16x32): B[k][col], lane: col=lane&15, k=(lane>>4)*8+i.
// ---------------------------------------------------------------------------
__global__ __launch_bounds__(256) void w1prep_k(
    const float* __restrict__ W1, unsigned short* __restrict__ W1b)
{
    for (int idx = threadIdx.x; idx < 16384; idx += 256) {
        int i    = idx & 7;
        int lane = (idx >> 3) & 63;
        int f    = (idx >> 9) & 7;
        int ks   = idx >> 12;
        int k   = ks * 32 + (lane >> 4) * 8 + i;
        int col = f * 16 + (lane & 15);
        W1b[idx] = f2bf(W1[k * 128 + col]);
    }
}

// ---------------------------------------------------------------------------
// GEMM1 (MFMA bf16): h1[N,128] = x @ W1, fp16 out; fused alpha reductions.
// Wave = 16 nodes x 128 cols: 4 K-steps x 8 col-frags of 16x16x32.
// A-frag: row=lane&15, k=(lane>>4)*8+i -> one short8 load from xb.
// C/D: col=lane&15, row=(lane>>4)*4+reg (m89-verified mapping).
// ---------------------------------------------------------------------------
__global__ __launch_bounds__(256) void gemm1_k(
    const unsigned short* __restrict__ xb, const unsigned short* __restrict__ W1b,
    const float* __restrict__ as1, const float* __restrict__ ad1,
    __half* __restrict__ h1h, float* __restrict__ asrc, float* __restrict__ adst)
{
    const int t = threadIdx.x;
    const int w = t >> 6, L = t & 63;
    const int lr = L & 15;            // A-row / C-col within frag
    const int lg = L >> 4;            // k-group / C row-group
    const int nbase = blockIdx.x * 64 + w * 16;

    float4v acc[8];
#pragma unroll
    for (int f = 0; f < 8; ++f) acc[f] = (float4v)0.f;

    int arow = nbase + lr; if (arow >= N_NODES) arow = N_NODES - 1;
    const unsigned short* xrow = xb + (size_t)arow * 128 + lg * 8;

#pragma unroll
    for (int ks = 0; ks < 4; ++ks) {
        short8v a = *(const short8v*)(xrow + ks * 32);
        const unsigned short* wb = W1b + ((size_t)ks * 8 * 64 + L) * 8;
#pragma unroll
        for (int f = 0; f < 8; ++f) {
            short8v b = *(const short8v*)(wb + (size_t)f * 512);
            acc[f] = __builtin_amdgcn_mfma_f32_16x16x32_bf16(a, b, acc[f], 0, 0, 0);
        }
    }

    float as_v[8], ad_v[8];
#pragma unroll
    for (int f = 0; f < 8; ++f) {
        as_v[f] = as1[f * 16 + lr];
        ad_v[f] = ad1[f * 16 + lr];
    }

#pragma unroll
    for (int r = 0; r < 4; ++r) {
        int node = nbase + lg * 4 + r;
        bool ok = node < N_NODES;
        if (ok) {
#pragma unroll
            for (int f = 0; f < 8; ++f)
                h1h[(size_t)node * 128 + f * 16 + lr] = __float2half_rn(acc[f][r]);
        }
        float ps0 = 0.f, pd0 = 0.f, ps1 = 0.f, pd1 = 0.f;
#pragma unroll
        for (int f = 0; f < 4; ++f) { ps0 += acc[f][r] * as_v[f]; pd0 += acc[f][r] * ad_v[f]; }
#pragma unroll
        for (int f = 4; f < 8; ++f) { ps1 += acc[f][r] * as_v[f]; pd1 += acc[f][r] * ad_v[f]; }
#pragma unroll
        for (int off = 1; off < 16; off <<= 1) {
            ps0 += __shfl_xor(ps0, off); pd0 += __shfl_xor(pd0, off);
            ps1 += __shfl_xor(ps1, off); pd1 += __shfl_xor(pd1, off);
        }
        if (lr == 0 && ok) {
            asrc[node * 2 + 0] = ps0; asrc[node * 2 + 1] = ps1;
            adst[node * 2 + 0] = pd0; adst[node * 2 + 1] = pd1;
        }
    }
}

// ---------------------------------------------------------------------------
// CSR build, phase 1: bin edges by dst bucket. Edges read ONCE into regs.
// ---------------------------------------------------------------------------
__global__ __launch_bounds__(256) void bin_k(
    const int* __restrict__ ei, int* __restrict__ bcur, unsigned* __restrict__ bdata)
{
    __shared__ int hist[NB];
    __shared__ int base[NB];
    const int t = threadIdx.x;
    const int e0 = blockIdx.x * BIN_CH;

    int rs[16], rd[16];
#pragma unroll
    for (int p = 0; p < 16; ++p) {
        int e = e0 + p * 256 + t;
        if (e < E_TOT) {
            if (e < N_EDGES) { rs[p] = ei[e]; rd[p] = ei[N_EDGES + e]; }
            else             { rs[p] = rd[p] = e - N_EDGES; }
        } else rd[p] = -1;
    }

    for (int b = t; b < NB; b += 256) hist[b] = 0;
    __syncthreads();

#pragma unroll
    for (int p = 0; p < 16; ++p)
        if (rd[p] >= 0) atomicAdd(&hist[rd[p] / NPB], 1);
    __syncthreads();

    for (int b = t; b < NB; b += 256) {
        int c = hist[b];
        base[b] = c ? atomicAdd(&bcur[b], c) : 0;
        hist[b] = 0;      // reuse as local cursor
    }
    __syncthreads();

#pragma unroll
    for (int p = 0; p < 16; ++p) {
        if (rd[p] < 0) continue;
        int b  = rd[p] / NPB;
        int dl = rd[p] - b * NPB;
        int pos = base[b] + atomicAdd(&hist[b], 1);
        if (pos < BCAP)
            bdata[(size_t)b * BCAP + pos] = (unsigned)rs[p] | ((unsigned)dl << 17);
    }
}

// ---------------------------------------------------------------------------
// CSR build, phase 2a: exclusive scan of bucket counts (1 wg x 512 threads).
// ---------------------------------------------------------------------------
__global__ __launch_bounds__(512) void scanb_k(
    const int* __restrict__ bcur, int* __restrict__ bbase)
{
    __shared__ int a[NB], b_[NB];
    int t = threadIdx.x;
    int v = bcur[t];
    a[t] = v;
    __syncthreads();
    int* src = a; int* dst = b_;
    for (int off = 1; off < NB; off <<= 1) {
        dst[t] = (t >= off) ? src[t - off] + src[t] : src[t];
        __syncthreads();
        int* tmp = src; src = dst; dst = tmp;
    }
    bbase[t] = src[t] - v;   // exclusive
}

// ---------------------------------------------------------------------------
// CSR build, phase 2b: wg per bucket -> row_start + csr_src (contiguous).
// ---------------------------------------------------------------------------
__global__ __launch_bounds__(256) void build_k(
    const unsigned* __restrict__ bdata, const int* __restrict__ bcur,
    const int* __restrict__ bbase, int* __restrict__ row_start,
    int* __restrict__ csr_src)
{
    __shared__ unsigned rec[BCAP];     // 16 KB
    __shared__ int hist[256];
    __shared__ int excl[NPB];
    __shared__ int lcur[NPB];
    const int t = threadIdx.x;
    const int b = blockIdx.x;
    const int cnt = min(bcur[b], BCAP);
    const int bb = bbase[b];

    hist[t] = 0;
    if (t < NPB) lcur[t] = 0;
    __syncthreads();

    for (int i = t; i < cnt; i += 256) {
        unsigned r = bdata[(size_t)b * BCAP + i];
        rec[i] = r;
        atomicAdd(&hist[r >> 17], 1);
    }
    __syncthreads();

    int v = hist[t];
    __syncthreads();
    for (int off = 1; off < 256; off <<= 1) {
        int y = (t >= off) ? hist[t - off] : 0;
        __syncthreads();
        hist[t] += y;
        __syncthreads();
    }
    if (t < NPB) excl[t] = hist[t] - v;
    __syncthreads();

    int node = b * NPB + t;
    if (t < NPB && node <= N_NODES) row_start[node] = bb + excl[t];

    for (int i = t; i < cnt; i += 256) {
        unsigned r = rec[i];
        int dl = r >> 17;
        int s  = r & 0x1FFFF;
        int slot = atomicAdd(&lcur[dl], 1);
        csr_src[bb + excl[dl] + slot] = s;
    }
}

// ---------------------------------------------------------------------------
// Fused layer-1 aggregation (round-7 form: inline exp, 4-wide, fp16 out).
// ---------------------------------------------------------------------------
__global__ __launch_bounds__(256) void fagg1_k(
    const int* __restrict__ csr_src, const int* __restrict__ row_start,
    const float* __restrict__ asrc, const float* __restrict__ adst,
    const __half* __restrict__ h1h, const float* __restrict__ b1,
    __half* __restrict__ out1h)
{
    int node = blockIdx.x * 4 + (threadIdx.x >> 6);
    int L = threadIdx.x & 63;
    int h = L >> 5;
    int b = row_start[node], e = row_start[node + 1];
    const float* as_h = asrc + h;
    float ad = adst[node * 2 + h];
    const __half2* H = (const __half2*)h1h;

    float2 a0 = make_float2(0.f, 0.f), a1 = a0, a2 = a0, a3 = a0;
    float d0 = 0.f, d1 = 0.f, d2 = 0.f, d3 = 0.f;

    int j = b;
    for (; j + 3 < e; j += 4) {
        int s0 = csr_src[j], s1 = csr_src[j + 1], s2 = csr_src[j + 2], s3 = csr_src[j + 3];
        float w0 = wexp(as_h[s0 * 2] + ad);
        float w1 = wexp(as_h[s1 * 2] + ad);
        float w2 = wexp(as_h[s2 * 2] + ad);
        float w3 = wexp(as_h[s3 * 2] + ad);
        float2 x0 = __half22float2(H[(size_t)s0 * 64 + L]);
        float2 x1 = __half22float2(H[(size_t)s1 * 64 + L]);
        float2 x2 = __half22float2(H[(size_t)s2 * 64 + L]);
        float2 x3 = __half22float2(H[(size_t)s3 * 64 + L]);
        a0.x += w0 * x0.x; a0.y += w0 * x0.y; d0 += w0;
        a1.x += w1 * x1.x; a1.y += w1 * x1.y; d1 += w1;
        a2.x += w2 * x2.x; a2.y += w2 * x2.y; d2 += w2;
        a3.x += w3 * x3.x; a3.y += w3 * x3.y; d3 += w3;
    }
    for (; j < e; ++j) {
        int s = csr_src[j];
        float w = wexp(as_h[s * 2] + ad);
        float2 xv = __half22float2(H[(size_t)s * 64 + L]);
        a0.x += w * xv.x; a0.y += w * xv.y; d0 += w;
    }

    float inv = 1.f / (((d0 + d1) + (d2 + d3)) + 1e-16f);
    float2 bb = ((const float2*)b1)[L];
    float vx = (a0.x + a1.x + a2.x + a3.x) * inv + bb.x;
    float vy = (a0.y + a1.y + a2.y + a3.y) * inv + bb.y;
    vx = vx > 0.f ? vx : expm1f(vx);
    vy = vy > 0.f ? vy : expm1f(vy);
    ((__half2*)(out1h + (size_t)node * 128))[L] = __floats2half2_rn(vx, vy);
}

// ---------------------------------------------------------------------------
// GEMM2 (LDS-tiled, scalar): h2[N,64pad fp16] = out1[N,128] @ W2[128,40].
// ---------------------------------------------------------------------------
__global__ __launch_bounds__(256) void gemm2_k(
    const __half* __restrict__ in1h, const float* __restrict__ W2,
    const float* __restrict__ as2, const float* __restrict__ ad2,
    __half* __restrict__ h2h, float* __restrict__ asrc, float* __restrict__ adst)
{
    __shared__ float xs[64][65];      // 16.6 KB
    __shared__ float Wsh[64][64];     // 16 KB
    __shared__ float as_s[64], ad_s[64];
    const int t = threadIdx.x;
    const int nbase = blockIdx.x * 64;
    const int c4 = t & 15;
    const int ng = t >> 4;

    if (t < 64) {
        as_s[t] = (t < 40) ? as2[t] : 0.f;
        ad_s[t] = (t < 40) ? ad2[t] : 0.f;
    }

    float acc[4][4];
#pragma unroll
    for (int i = 0; i < 4; ++i)
#pragma unroll
        for (int j = 0; j < 4; ++j) acc[i][j] = 0.f;

    for (int kt = 0; kt < 128; kt += 64) {
        __syncthreads();
        {
            int r = t >> 4;
            int c = (t & 15) * 4;
#pragma unroll
            for (int p = 0; p < 4; ++p) {
                int row = p * 16 + r;
                int gr = nbase + row; if (gr > N_NODES - 1) gr = N_NODES - 1;
                const __half2* src = (const __half2*)(in1h + (size_t)gr * 128 + kt + c);
                float2 f01 = __half22float2(src[0]);
                float2 f23 = __half22float2(src[1]);
                xs[row][c + 0] = f01.x; xs[row][c + 1] = f01.y;
                xs[row][c + 2] = f23.x; xs[row][c + 3] = f23.y;
            }
        }
        for (int i = t; i < 4096; i += 256) {
            int k = i >> 6, c = i & 63;
            Wsh[k][c] = (c < 40) ? W2[(size_t)(kt + k) * 40 + c] : 0.f;
        }
        __syncthreads();

#pragma unroll 4
        for (int k = 0; k < 64; ++k) {
            float4 w = *(const float4*)&Wsh[k][c4 * 4];
            float x0 = xs[ng * 4 + 0][k], x1 = xs[ng * 4 + 1][k];
            float x2 = xs[ng * 4 + 2][k], x3 = xs[ng * 4 + 3][k];
            acc[0][0] += x0 * w.x; acc[0][1] += x0 * w.y; acc[0][2] += x0 * w.z; acc[0][3] += x0 * w.w;
            acc[1][0] += x1 * w.x; acc[1][1] += x1 * w.y; acc[1][2] += x1 * w.z; acc[1][3] += x1 * w.w;
            acc[2][0] += x2 * w.x; acc[2][1] += x2 * w.y; acc[2][2] += x2 * w.z; acc[2][3] += x2 * w.w;
            acc[3][0] += x3 * w.x; acc[3][1] += x3 * w.y; acc[3][2] += x3 * w.z; acc[3][3] += x3 * w.w;
        }
    }

    float4 as4 = *(const float4*)&as_s[c4 * 4];
    float4 ad4 = *(const float4*)&ad_s[c4 * 4];
#pragma unroll
    for (int i = 0; i < 4; ++i) {
        int node = nbase + ng * 4 + i;
        float axx = acc[i][0], ayy = acc[i][1], azz = acc[i][2], aww = acc[i][3];
        if (node < N_NODES) {
            __half2* row = (__half2*)(h2h + (size_t)node * 64);
            row[2 * c4]     = __floats2half2_rn(axx, ayy);
            row[2 * c4 + 1] = __floats2half2_rn(azz, aww);
        }
        float ps = axx * as4.x + ayy * as4.y + azz * as4.z + aww * as4.w;
        float pd = axx * ad4.x + ayy * ad4.y + azz * ad4.z + aww * ad4.w;
#pragma unroll
        for (int off = 1; off < 16; off <<= 1) {
            ps += __shfl_xor(ps, off);
            pd += __shfl_xor(pd, off);
        }
        if ((t & 15) == 0 && node < N_NODES) {
            asrc[node] = ps;
            adst[node] = pd;
        }
    }
}

// ---------------------------------------------------------------------------
// Fused layer-2 aggregation + bias + log_softmax (round-7 form).
// ---------------------------------------------------------------------------
__global__ __launch_bounds__(256) void fagg2_k(
    const int* __restrict__ csr_src, const int* __restrict__ row_start,
    const float* __restrict__ asrc, const float* __restrict__ adst,
    const __half* __restrict__ h2h, const float* __restrict__ b2,
    float* __restrict__ out)
{
    int node = blockIdx.x * 4 + (threadIdx.x >> 6);
    int L = threadIdx.x & 63;
    bool act = L < 40;
    int col = act ? L : 0;
    int b = row_start[node], e = row_start[node + 1];
    float ad = adst[node];

    float a0 = 0.f, a1 = 0.f, a2 = 0.f, a3 = 0.f;
    float d0 = 0.f, d1 = 0.f, d2 = 0.f, d3 = 0.f;

    int j = b;
    for (; j + 3 < e; j += 4) {
        int s0 = csr_src[j], s1 = csr_src[j + 1], s2 = csr_src[j + 2], s3 = csr_src[j + 3];
        float w0 = wexp(asrc[s0] + ad);
        float w1 = wexp(asrc[s1] + ad);
        float w2 = wexp(asrc[s2] + ad);
        float w3 = wexp(asrc[s3] + ad);
        float x0 = __half2float(h2h[(size_t)s0 * 64 + col]);
        float x1 = __half2float(h2h[(size_t)s1 * 64 + col]);
        float x2 = __half2float(h2h[(size_t)s2 * 64 + col]);
        float x3 = __half2float(h2h[(size_t)s3 * 64 + col]);
        a0 += w0 * x0; d0 += w0;
        a1 += w1 * x1; d1 += w1;
        a2 += w2 * x2; d2 += w2;
        a3 += w3 * x3; d3 += w3;
    }
    for (; j < e; ++j) {
        int s = csr_src[j];
        float w = wexp(asrc[s] + ad);
        float xv = __half2float(h2h[(size_t)s * 64 + col]);
        a0 += w * xv; d0 += w;
    }

    float den = (d0 + d1) + (d2 + d3);
    float acc = (a0 + a1) + (a2 + a3);
    float v = act ? acc / (den + 1e-16f) + b2[L] : -1e30f;
    float mx = v;
#pragma unroll
    for (int off = 32; off; off >>= 1) mx = fmaxf(mx, __shfl_xor(mx, off));
    float ex = act ? __expf(v - mx) : 0.f;
#pragma unroll
    for (int off = 32; off; off >>= 1) ex += __shfl_xor(ex, off);
    if (act) out[(size_t)node * 40 + L] = v - mx - logf(ex);
}

// ---------------------------------------------------------------------------
extern "C" void kernel_launch(void* const* d_in, const int* in_sizes, int n_in,
                              void* d_out, int out_size, void* d_ws, size_t ws_size,
                              hipStream_t stream)
{
    const float* x   = (const float*)d_in[0];
    const int*   ei  = (const int*)d_in[1];
    const float* W1  = (const float*)d_in[2];
    const float* as1 = (const float*)d_in[3];
    const float* ad1 = (const float*)d_in[4];
    const float* b1  = (const float*)d_in[5];
    const float* W2  = (const float*)d_in[6];
    const float* as2 = (const float*)d_in[7];
    const float* ad2 = (const float*)d_in[8];
    const float* b2  = (const float*)d_in[9];
    float* out = (float*)d_out;

    float* ws = (float*)d_ws;
    // workspace layout (4B units); total ~27.4M = 109.6 MB
    __half* h1h   = (__half*)ws;                  // N*128 halves; reused as h2h (N*64 halves)
    __half* out1h = (__half*)(ws + 6400000);      // N*128 halves
    float* asrc1 = ws + 19200000;                 // 2N
    float* adst1 = ws + 19400000;                 // 2N
    float* asrc2 = ws + 19600000;                 // N
    float* adst2 = ws + 19700000;                 // N
    int* bcur      = (int*)(ws + 20110000);       // NB
    int* bbase     = (int*)(ws + 20111000);       // NB
    int* row_start = (int*)(ws + 20112000);       // N+1
    int* csr_src   = (int*)(ws + 20220000);       // E_TOT
    unsigned* bdata = (unsigned*)(ws + 22000000); // NB*BCAP = 2.1M
    unsigned short* xb  = (unsigned short*)(ws + 24100000);  // N*128 bf16 = 3.2M units
    unsigned short* W1b = (unsigned short*)(ws + 27300000);  // 16384 bf16

    // zero bucket cursors only (2 KB)
    hipMemsetAsync(bcur, 0, NB * sizeof(int), stream);

    // prep: x -> bf16, W1 -> bf16 fragment order
    xprep_k<<<12500, 256, 0, stream>>>(x, xb);
    w1prep_k<<<1, 256, 0, stream>>>(W1, W1b);

    // CSR build: bin -> scan -> build
    bin_k<<<NBIN_WG, 256, 0, stream>>>(ei, bcur, bdata);
    scanb_k<<<1, 512, 0, stream>>>(bcur, bbase);
    build_k<<<NB, 256, 0, stream>>>(bdata, bcur, bbase, row_start, csr_src);

    // layer 1
    gemm1_k<<<1563, 256, 0, stream>>>(xb, W1b, as1, ad1, h1h, asrc1, adst1);
    fagg1_k<<<25000, 256, 0, stream>>>(csr_src, row_start, asrc1, adst1, h1h, b1, out1h);

    // layer 2 (h2h reuses h1h region, stride 64 halves = one 128B line)
    __half* h2h = h1h;
    gemm2_k<<<1563, 256, 0, stream>>>(out1h, W2, as2, ad2, h2h, asrc2, adst2);
    fagg2_k<<<25000, 256, 0, stream>>>(csr_src, row_start, asrc2, adst2, h2h, b2, out);
}